// Round 6
// baseline (186.734 us; speedup 1.0000x reference)
//
#include <hip/hip_runtime.h>
#include <hip/hip_bf16.h>
#include <float.h>

// AFM via MFMA, round 6: occupancy + de-serialized softmax.
// One wave owns 2 rows (RPW=2 -> 2048 blocks -> 8 blocks/CU; round-5's RPW=4
// capped the grid at 4 blocks/CU = 41% occupancy, latency-bound). Per 32-pair
// tile: one v_mfma_f32_32x32x16_bf16 computes h^T = W^T@inner^T with bias
// preloaded in the accumulator; per-pair cross scalar g_p = inner_p . fc_w
// folded into the same pass. Scores are kept PARTIAL (own e-half) in sc[9] --
// no per-tile shfl/expf chain (round-5's online softmax serialized every
// tile). Epilogue per row: 9 batched half-combines, max, 9 independent expf.
// bf16 by truncation (v_perm), error ~1e-5 vs 2.2e-2 threshold.

#define FN 24
#define ED 16
#define AS 32
#define NP 276
#define NT 9            // 32-pair tiles (288 slots)
#define LASTV 20        // valid cols in last tile
#define EPITCH 20       // emb LDS row pitch in words (80 B, b128-aligned)
#define RPW 2           // rows per wave
#define NTHR 256
#define FIELD_SIZE 50000

typedef __attribute__((ext_vector_type(8)))  short bf16x8;
typedef __attribute__((ext_vector_type(16))) float f32x16;
typedef __attribute__((ext_vector_type(2)))  float f32x2;

union BFR { int i[4]; bf16x8 v; };

__device__ __forceinline__ short f2bf(float x) {
    union { __hip_bfloat16 h; short s; } u;
    u.h = __float2bfloat16(x);
    return u.s;
}

__device__ __forceinline__ void gather_embed(const float* __restrict__ et,
                                             int idxv, int lane,
                                             float4& a, float4& b) {
    const int f0 = lane >> 2, q0 = lane & 3;
    const int id0 = __shfl(idxv, f0, 64);
    const int id1 = __shfl(idxv, 16 + f0, 64);   // meaningful for lane<32
    a = ((const float4*)(et + (size_t)id0 * ED))[q0];
    if (lane < 32)
        b = ((const float4*)(et + (size_t)id1 * ED))[q0];
}

__device__ __forceinline__ void write_embed(float* __restrict__ buf, int lane,
                                            const float4& a, const float4& b) {
    const int f0 = lane >> 2, q0 = lane & 3;
    *(float4*)&buf[f0 * EPITCH + q0 * 4] = a;
    if (lane < 32)
        *(float4*)&buf[(16 + f0) * EPITCH + q0 * 4] = b;
}

__global__ __launch_bounds__(NTHR, 6) void afm_kernel(
    const int*   __restrict__ x,
    const float* __restrict__ embed_table,
    const float* __restrict__ linear_table,
    const float* __restrict__ linear_bias,
    const float* __restrict__ attn_W,       // [E, A]
    const float* __restrict__ attn_b,       // [A]
    const float* __restrict__ proj_w,       // [A]
    const float* __restrict__ fc_w,         // [E]
    const float* __restrict__ fc_b,
    float*       __restrict__ out,
    int B)
{
    __shared__ float emb_s[NTHR / 64][2][FN * EPITCH];
    __shared__ int   pko_s[NT * 32];

    const int tid  = threadIdx.x;
    const int wave = tid >> 6;
    const int lane = tid & 63;
    const int half = lane >> 5;
    const int col  = lane & 31;
    const int e0   = half * 8;
    const int w0   = (blockIdx.x * (NTHR / 64) + wave) * RPW;

    // ---- pair table, block-cooperative ----
    for (int s = tid; s < NT * 32; s += NTHR) {
        const int p = (s < NP) ? s : (NP - 1);
        const int q = (NP - 1) - p;
        int m = (int)((sqrtf((float)(8 * q + 1)) + 1.0f) * 0.5f);
        if (m * (m + 1) / 2 <= q) ++m;
        if ((m - 1) * m / 2 > q) --m;
        const int fi = (FN - 1) - m;
        const int fj = fi + 1 + (p - (NP - m * (m + 1) / 2));
        pko_s[s] = ((fi * (EPITCH * 4)) << 16) | (fj * (EPITCH * 4));
    }

    // ---- prologue: x loads for both rows ----
    int idxr[RPW];
#pragma unroll
    for (int k = 0; k < RPW; ++k) {
        const int r = w0 + k, rc = (r < B) ? r : (B - 1);
        idxr[k] = (lane < FN) ? (x[rc * FN + lane] + lane * FIELD_SIZE) : 0;
    }

    // ---- per-lane weight constants (amortized over 2 rows) ----
    bf16x8 aW;                          // A-frag: W^T[a=col][k=e0+i]
#pragma unroll
    for (int i = 0; i < 8; ++i) aW[i] = f2bf(attn_W[(e0 + i) * AS + col]);
    float b16[16], pw16[16];            // D rows: a=(r&3)+8*(r>>2)+4*half
#pragma unroll
    for (int r = 0; r < 16; ++r) {
        const int a = (r & 3) + 8 * (r >> 2) + 4 * half;
        b16[r]  = attn_b[a];
        pw16[r] = proj_w[a];
    }
    float fcw[8];
#pragma unroll
    for (int i = 0; i < 8; ++i) fcw[i] = fc_w[e0 + i];
    const float cbias = linear_bias[0] + fc_b[0];

    // ---- prologue: row 0 gather + LDS write ----
    float linv = (lane < FN) ? linear_table[idxr[0]] : 0.f;
    {
        float4 ga, gb;
        gather_embed(embed_table, idxr[0], lane, ga, gb);
        write_embed(emb_s[wave][0], lane, ga, gb);
    }

    __syncthreads();                    // pko_s ready
    int pk[NT];
#pragma unroll
    for (int t = 0; t < NT; ++t) pk[t] = pko_s[t * 32 + col];

    // ---- main loop over this wave's rows ----
#pragma unroll
    for (int k = 0; k < RPW; ++k) {
        const int row = w0 + k;
        // prefetch next row (gather overlaps this row's compute)
        float4 na, nb; float linn = 0.f;
        if (k + 1 < RPW) {
            linn = (lane < FN) ? linear_table[idxr[k + 1]] : 0.f;
            gather_embed(embed_table, idxr[k + 1], lane, na, nb);
        }

        const char* embb = (const char*)emb_s[wave][k & 1] + half * 32;
        float sc[NT], g[NT];
#pragma unroll
        for (int t = 0; t < NT; ++t) {
            const int oi = pk[t] >> 16;
            const int oj = pk[t] & 0xffff;
            const float4 xi0 = *(const float4*)(embb + oi);
            const float4 xi1 = *(const float4*)(embb + oi + 16);
            const float4 xj0 = *(const float4*)(embb + oj);
            const float4 xj1 = *(const float4*)(embb + oj + 16);
            const float p0 = xi0.x * xj0.x, p1 = xi0.y * xj0.y;
            const float p2 = xi0.z * xj0.z, p3 = xi0.w * xj0.w;
            const float p4 = xi1.x * xj1.x, p5 = xi1.y * xj1.y;
            const float p6 = xi1.z * xj1.z, p7 = xi1.w * xj1.w;
            float gv = p0 * fcw[0];
            gv = fmaf(p1, fcw[1], gv); gv = fmaf(p2, fcw[2], gv);
            gv = fmaf(p3, fcw[3], gv); gv = fmaf(p4, fcw[4], gv);
            gv = fmaf(p5, fcw[5], gv); gv = fmaf(p6, fcw[6], gv);
            gv = fmaf(p7, fcw[7], gv);
            g[t] = gv;
            BFR u;
            u.i[0] = __builtin_amdgcn_perm(__float_as_int(p1), __float_as_int(p0), 0x07060302);
            u.i[1] = __builtin_amdgcn_perm(__float_as_int(p3), __float_as_int(p2), 0x07060302);
            u.i[2] = __builtin_amdgcn_perm(__float_as_int(p5), __float_as_int(p4), 0x07060302);
            u.i[3] = __builtin_amdgcn_perm(__float_as_int(p7), __float_as_int(p6), 0x07060302);
            f32x16 c;
#pragma unroll
            for (int r = 0; r < 16; ++r) c[r] = b16[r];
            c = __builtin_amdgcn_mfma_f32_32x32x16_bf16(aW, u.v, c, 0, 0, 0);
            f32x2 sac; sac.x = 0.f; sac.y = 0.f;
            f32x2 z2;  z2.x = 0.f;  z2.y = 0.f;
#pragma unroll
            for (int r2 = 0; r2 < 8; ++r2) {
                f32x2 h; h.x = c[2 * r2]; h.y = c[2 * r2 + 1];
                h = __builtin_elementwise_max(h, z2);
                f32x2 pw; pw.x = pw16[2 * r2]; pw.y = pw16[2 * r2 + 1];
                sac = __builtin_elementwise_fma(h, pw, sac);
            }
            sc[t] = sac.x + sac.y;      // PARTIAL score (own a-half)
        }

        // ---- epilogue: batched half-combine, softmax, reductions ----
#pragma unroll
        for (int t = 0; t < NT; ++t) sc[t] += __shfl_xor(sc[t], 32, 64);
        float M = sc[0];
#pragma unroll
        for (int t = 1; t < NT - 1; ++t) M = fmaxf(M, sc[t]);
        M = fmaxf(M, (col < LASTV) ? sc[NT - 1] : sc[0]);
#pragma unroll
        for (int off = 16; off; off >>= 1) M = fmaxf(M, __shfl_xor(M, off, 64));
        float ssum = 0.f, cp = 0.f;
#pragma unroll
        for (int t = 0; t < NT; ++t) {
            float e = __expf(sc[t] - M);
            if (t == NT - 1) e = (col < LASTV) ? e : 0.f;
            ssum += e;
            cp = fmaf(e, g[t], cp);
        }
#pragma unroll
        for (int off = 16; off; off >>= 1) ssum += __shfl_xor(ssum, off, 64);
#pragma unroll
        for (int off = 32; off; off >>= 1) cp += __shfl_xor(cp, off, 64);
        float lin = linv;
#pragma unroll
        for (int off = 32; off; off >>= 1) lin += __shfl_xor(lin, off, 64);

        if (row < B && lane == 0)
            out[row] = lin + cbias + cp / ssum;

        if (k + 1 < RPW) {
            write_embed(emb_s[wave][(k + 1) & 1], lane, na, nb);
            linv = linn;
        }
    }
}

extern "C" void kernel_launch(void* const* d_in, const int* in_sizes, int n_in,
                              void* d_out, int out_size, void* d_ws, size_t ws_size,
                              hipStream_t stream) {
    const int*   x            = (const int*)  d_in[0];
    const float* embed_table  = (const float*)d_in[1];
    const float* linear_table = (const float*)d_in[2];
    const float* linear_bias  = (const float*)d_in[3];
    const float* attn_W       = (const float*)d_in[4];
    const float* attn_b       = (const float*)d_in[5];
    const float* proj_w       = (const float*)d_in[6];
    // d_in[7] = proj_b (softmax-invariant)
    const float* fc_w         = (const float*)d_in[8];
    const float* fc_b         = (const float*)d_in[9];
    float* out = (float*)d_out;

    const int B = in_sizes[0] / FN;
    const int rows_per_block = (NTHR / 64) * RPW;   // 8
    const int grid = (B + rows_per_block - 1) / rows_per_block;
    afm_kernel<<<grid, NTHR, 0, stream>>>(x, embed_table, linear_table,
                                          linear_bias, attn_W, attn_b, proj_w,
                                          fc_w, fc_b, out, B);
}

// Round 7
// 143.065 us; speedup vs baseline: 1.3052x; 1.3052x over previous
//
#include <hip/hip_runtime.h>
#include <hip/hip_bf16.h>
#include <float.h>

// AFM via MFMA, round 7 = round-5 structure (proven VGPR=64, no spills) with
// RPW=2 for occupancy. Round-6 lesson: launch_bounds(256,6) + sc/g arrays
// spilled to scratch (WRITE_SIZE 170KB->109MB) -- keep online softmax (3 live
// scalars) and let TLP (8 waves/SIMD at 64 VGPR) hide the per-tile serial
// chain instead of registers. RPW=2 -> 2048 blocks -> 8 blocks/CU -> 32
// waves/CU available (round-5's RPW=4 grid capped at 16). LDS 16.5KB x 8
// blocks = 132KB < 160KB.
// Per 32-pair tile: one v_mfma_f32_32x32x16_bf16 computes h^T = W^T@inner^T
// (bias preloaded in accumulator); cross term folded via g_p = inner_p.fc_w.
// bf16 by truncation (v_perm), error ~1e-5 vs 2.2e-2 threshold.

#define FN 24
#define ED 16
#define AS 32
#define NP 276
#define NT 9            // 32-pair tiles (288 slots)
#define LASTV 20        // valid cols in last tile
#define EPITCH 20       // emb LDS row pitch in words (80 B, b128-aligned)
#define RPW 2           // rows per wave
#define NTHR 256
#define FIELD_SIZE 50000

typedef __attribute__((ext_vector_type(8)))  short bf16x8;
typedef __attribute__((ext_vector_type(16))) float f32x16;
typedef __attribute__((ext_vector_type(2)))  float f32x2;

union BFR { int i[4]; bf16x8 v; };

__device__ __forceinline__ short f2bf(float x) {
    union { __hip_bfloat16 h; short s; } u;
    u.h = __float2bfloat16(x);
    return u.s;
}

__device__ __forceinline__ void gather_embed(const float* __restrict__ et,
                                             int idxv, int lane,
                                             float4& a, float4& b) {
    const int f0 = lane >> 2, q0 = lane & 3;
    const int id0 = __shfl(idxv, f0, 64);
    const int id1 = __shfl(idxv, 16 + f0, 64);   // meaningful for lane<32
    a = ((const float4*)(et + (size_t)id0 * ED))[q0];
    if (lane < 32)
        b = ((const float4*)(et + (size_t)id1 * ED))[q0];
}

__device__ __forceinline__ void write_embed(float* __restrict__ buf, int lane,
                                            const float4& a, const float4& b) {
    const int f0 = lane >> 2, q0 = lane & 3;
    *(float4*)&buf[f0 * EPITCH + q0 * 4] = a;
    if (lane < 32)
        *(float4*)&buf[(16 + f0) * EPITCH + q0 * 4] = b;
}

__global__ __launch_bounds__(NTHR, 4) void afm_kernel(
    const int*   __restrict__ x,
    const float* __restrict__ embed_table,
    const float* __restrict__ linear_table,
    const float* __restrict__ linear_bias,
    const float* __restrict__ attn_W,       // [E, A]
    const float* __restrict__ attn_b,       // [A]
    const float* __restrict__ proj_w,       // [A]
    const float* __restrict__ fc_w,         // [E]
    const float* __restrict__ fc_b,
    float*       __restrict__ out,
    int B)
{
    __shared__ float emb_s[NTHR / 64][2][FN * EPITCH];
    __shared__ int   pko_s[NT * 32];

    const int tid  = threadIdx.x;
    const int wave = tid >> 6;
    const int lane = tid & 63;
    const int half = lane >> 5;
    const int col  = lane & 31;
    const int e0   = half * 8;
    const int w0   = (blockIdx.x * (NTHR / 64) + wave) * RPW;

    // ---- pair table, block-cooperative ----
    for (int s = tid; s < NT * 32; s += NTHR) {
        const int p = (s < NP) ? s : (NP - 1);
        const int q = (NP - 1) - p;
        int m = (int)((sqrtf((float)(8 * q + 1)) + 1.0f) * 0.5f);
        if (m * (m + 1) / 2 <= q) ++m;
        if ((m - 1) * m / 2 > q) --m;
        const int fi = (FN - 1) - m;
        const int fj = fi + 1 + (p - (NP - m * (m + 1) / 2));
        pko_s[s] = ((fi * (EPITCH * 4)) << 16) | (fj * (EPITCH * 4));
    }

    // ---- prologue: x loads for this wave's rows ----
    int idxr[RPW];
#pragma unroll
    for (int k = 0; k < RPW; ++k) {
        const int r = w0 + k, rc = (r < B) ? r : (B - 1);
        idxr[k] = (lane < FN) ? (x[rc * FN + lane] + lane * FIELD_SIZE) : 0;
    }

    // ---- per-lane weight constants (amortized over RPW rows) ----
    bf16x8 aW;                          // A-frag: W^T[a=col][k=e0+i]
#pragma unroll
    for (int i = 0; i < 8; ++i) aW[i] = f2bf(attn_W[(e0 + i) * AS + col]);
    float b16[16], pw16[16];            // D rows: a=(r&3)+8*(r>>2)+4*half
#pragma unroll
    for (int r = 0; r < 16; ++r) {
        const int a = (r & 3) + 8 * (r >> 2) + 4 * half;
        b16[r]  = attn_b[a];
        pw16[r] = proj_w[a];
    }
    float fcw[8];
#pragma unroll
    for (int i = 0; i < 8; ++i) fcw[i] = fc_w[e0 + i];
    const float cbias = linear_bias[0] + fc_b[0];

    // ---- prologue: row 0 gather + LDS write ----
    float linv = (lane < FN) ? linear_table[idxr[0]] : 0.f;
    {
        float4 ga, gb;
        gather_embed(embed_table, idxr[0], lane, ga, gb);
        write_embed(emb_s[wave][0], lane, ga, gb);
    }

    __syncthreads();                    // pko_s ready
    int pk[NT];
#pragma unroll
    for (int t = 0; t < NT; ++t) pk[t] = pko_s[t * 32 + col];

    // ---- main loop over this wave's rows ----
#pragma unroll
    for (int k = 0; k < RPW; ++k) {
        const int row = w0 + k;
        // prefetch next row (gather overlaps this row's compute)
        float4 na, nb; float linn = 0.f;
        if (k + 1 < RPW) {
            linn = (lane < FN) ? linear_table[idxr[k + 1]] : 0.f;
            gather_embed(embed_table, idxr[k + 1], lane, na, nb);
        }

        const char* embb = (const char*)emb_s[wave][k & 1] + half * 32;
        float m = -FLT_MAX, ssum = 0.f, gacc = 0.f;
#pragma unroll
        for (int t = 0; t < NT; ++t) {
            const int oi = pk[t] >> 16;
            const int oj = pk[t] & 0xffff;
            const float4 xi0 = *(const float4*)(embb + oi);
            const float4 xi1 = *(const float4*)(embb + oi + 16);
            const float4 xj0 = *(const float4*)(embb + oj);
            const float4 xj1 = *(const float4*)(embb + oj + 16);
            const float p0 = xi0.x * xj0.x, p1 = xi0.y * xj0.y;
            const float p2 = xi0.z * xj0.z, p3 = xi0.w * xj0.w;
            const float p4 = xi1.x * xj1.x, p5 = xi1.y * xj1.y;
            const float p6 = xi1.z * xj1.z, p7 = xi1.w * xj1.w;
            float gv = p0 * fcw[0];
            gv = fmaf(p1, fcw[1], gv); gv = fmaf(p2, fcw[2], gv);
            gv = fmaf(p3, fcw[3], gv); gv = fmaf(p4, fcw[4], gv);
            gv = fmaf(p5, fcw[5], gv); gv = fmaf(p6, fcw[6], gv);
            gv = fmaf(p7, fcw[7], gv);
            BFR u;
            u.i[0] = __builtin_amdgcn_perm(__float_as_int(p1), __float_as_int(p0), 0x07060302);
            u.i[1] = __builtin_amdgcn_perm(__float_as_int(p3), __float_as_int(p2), 0x07060302);
            u.i[2] = __builtin_amdgcn_perm(__float_as_int(p5), __float_as_int(p4), 0x07060302);
            u.i[3] = __builtin_amdgcn_perm(__float_as_int(p7), __float_as_int(p6), 0x07060302);
            f32x16 c;
#pragma unroll
            for (int r = 0; r < 16; ++r) c[r] = b16[r];
            c = __builtin_amdgcn_mfma_f32_32x32x16_bf16(aW, u.v, c, 0, 0, 0);
            f32x2 sac; sac.x = 0.f; sac.y = 0.f;
            f32x2 z2;  z2.x = 0.f;  z2.y = 0.f;
#pragma unroll
            for (int r2 = 0; r2 < 8; ++r2) {
                f32x2 h; h.x = c[2 * r2]; h.y = c[2 * r2 + 1];
                h = __builtin_elementwise_max(h, z2);
                f32x2 pw; pw.x = pw16[2 * r2]; pw.y = pw16[2 * r2 + 1];
                sac = __builtin_elementwise_fma(h, pw, sac);
            }
            float s = sac.x + sac.y;
            s += __shfl_xor(s, 32, 64);        // combine the two a-halves
            const bool valid = (t < NT - 1) || (col < LASTV);
            s = valid ? s : -FLT_MAX;
            // online softmax update (3 live scalars; keeps VGPR at 64)
            const float mn   = fmaxf(m, s);
            const float cold = __expf(m - mn);
            const float e    = __expf(s - mn);
            ssum = fmaf(ssum, cold, e);
            gacc = fmaf(gacc, cold, e * gv);
            m = mn;
        }

        // ---- reductions: max (half), rescale, sums ----
        float M = m;
#pragma unroll
        for (int off = 16; off; off >>= 1) M = fmaxf(M, __shfl_xor(M, off, 64));
        const float rs = __expf(m - M);
        ssum *= rs; gacc *= rs;
#pragma unroll
        for (int off = 16; off; off >>= 1) ssum += __shfl_xor(ssum, off, 64);
#pragma unroll
        for (int off = 32; off; off >>= 1) gacc += __shfl_xor(gacc, off, 64);
        float lin = linv;
#pragma unroll
        for (int off = 32; off; off >>= 1) lin += __shfl_xor(lin, off, 64);

        if (row < B && lane == 0)
            out[row] = lin + cbias + gacc / ssum;

        // stage next row's embeddings into the other buffer
        if (k + 1 < RPW) {
            write_embed(emb_s[wave][(k + 1) & 1], lane, na, nb);
            linv = linn;
        }
    }
}

extern "C" void kernel_launch(void* const* d_in, const int* in_sizes, int n_in,
                              void* d_out, int out_size, void* d_ws, size_t ws_size,
                              hipStream_t stream) {
    const int*   x            = (const int*)  d_in[0];
    const float* embed_table  = (const float*)d_in[1];
    const float* linear_table = (const float*)d_in[2];
    const float* linear_bias  = (const float*)d_in[3];
    const float* attn_W       = (const float*)d_in[4];
    const float* attn_b       = (const float*)d_in[5];
    const float* proj_w       = (const float*)d_in[6];
    // d_in[7] = proj_b (softmax-invariant)
    const float* fc_w         = (const float*)d_in[8];
    const float* fc_b         = (const float*)d_in[9];
    float* out = (float*)d_out;

    const int B = in_sizes[0] / FN;
    const int rows_per_block = (NTHR / 64) * RPW;   // 8
    const int grid = (B + rows_per_block - 1) / rows_per_block;
    afm_kernel<<<grid, NTHR, 0, stream>>>(x, embed_table, linear_table,
                                          linear_bias, attn_W, attn_b, proj_w,
                                          fc_w, fc_b, out, B);
}

// Round 8
// 142.846 us; speedup vs baseline: 1.3072x; 1.0015x over previous
//
#include <hip/hip_runtime.h>
#include <hip/hip_bf16.h>
#include <float.h>

// AFM via MFMA, round 8 = round-7 structure + two instruction-count cuts:
// (1) bias vector passed DIRECTLY as the MFMA C operand (MAI has separate
//     D/C register fields) -- kills the 16 v_mov C-init per tile (144/row);
// (2) packed-f32 math: products as 4 v_pk_mul_f32 and the fc-dot as
//     4 v_pk_fma_f32 + 1 hadd (was 8 mul + 8 fma).
// Proven bones kept: one wave owns 2 rows (2048 blocks -> 8 blocks/CU,
// 8 waves/SIMD at 64 VGPR), online softmax (3 live scalars, no spill --
// round-6 lesson), per-wave LDS double buffer with next-row gather prefetch,
// g_p = inner_p . fc_w cross-term folding, bf16 by truncation via v_perm
// (error ~1e-5 vs 2.2e-2 threshold).

#define FN 24
#define ED 16
#define AS 32
#define NP 276
#define NT 9            // 32-pair tiles (288 slots)
#define LASTV 20        // valid cols in last tile
#define EPITCH 20       // emb LDS row pitch in words (80 B, b128-aligned)
#define RPW 2           // rows per wave
#define NTHR 256
#define FIELD_SIZE 50000

typedef __attribute__((ext_vector_type(8)))  short bf16x8;
typedef __attribute__((ext_vector_type(16))) float f32x16;
typedef __attribute__((ext_vector_type(2)))  float f32x2;

union BFR { int i[4]; bf16x8 v; };
union F4P { float4 f4; f32x2 p[2]; };

__device__ __forceinline__ short f2bf(float x) {
    union { __hip_bfloat16 h; short s; } u;
    u.h = __float2bfloat16(x);
    return u.s;
}

__device__ __forceinline__ void gather_embed(const float* __restrict__ et,
                                             int idxv, int lane,
                                             float4& a, float4& b) {
    const int f0 = lane >> 2, q0 = lane & 3;
    const int id0 = __shfl(idxv, f0, 64);
    const int id1 = __shfl(idxv, 16 + f0, 64);   // meaningful for lane<32
    a = ((const float4*)(et + (size_t)id0 * ED))[q0];
    if (lane < 32)
        b = ((const float4*)(et + (size_t)id1 * ED))[q0];
}

__device__ __forceinline__ void write_embed(float* __restrict__ buf, int lane,
                                            const float4& a, const float4& b) {
    const int f0 = lane >> 2, q0 = lane & 3;
    *(float4*)&buf[f0 * EPITCH + q0 * 4] = a;
    if (lane < 32)
        *(float4*)&buf[(16 + f0) * EPITCH + q0 * 4] = b;
}

__global__ __launch_bounds__(NTHR, 4) void afm_kernel(
    const int*   __restrict__ x,
    const float* __restrict__ embed_table,
    const float* __restrict__ linear_table,
    const float* __restrict__ linear_bias,
    const float* __restrict__ attn_W,       // [E, A]
    const float* __restrict__ attn_b,       // [A]
    const float* __restrict__ proj_w,       // [A]
    const float* __restrict__ fc_w,         // [E]
    const float* __restrict__ fc_b,
    float*       __restrict__ out,
    int B)
{
    __shared__ float emb_s[NTHR / 64][2][FN * EPITCH];
    __shared__ int   pko_s[NT * 32];

    const int tid  = threadIdx.x;
    const int wave = tid >> 6;
    const int lane = tid & 63;
    const int half = lane >> 5;
    const int col  = lane & 31;
    const int e0   = half * 8;
    const int w0   = (blockIdx.x * (NTHR / 64) + wave) * RPW;

    // ---- pair table, block-cooperative ----
    for (int s = tid; s < NT * 32; s += NTHR) {
        const int p = (s < NP) ? s : (NP - 1);
        const int q = (NP - 1) - p;
        int m = (int)((sqrtf((float)(8 * q + 1)) + 1.0f) * 0.5f);
        if (m * (m + 1) / 2 <= q) ++m;
        if ((m - 1) * m / 2 > q) --m;
        const int fi = (FN - 1) - m;
        const int fj = fi + 1 + (p - (NP - m * (m + 1) / 2));
        pko_s[s] = ((fi * (EPITCH * 4)) << 16) | (fj * (EPITCH * 4));
    }

    // ---- prologue: x loads for this wave's rows ----
    int idxr[RPW];
#pragma unroll
    for (int k = 0; k < RPW; ++k) {
        const int r = w0 + k, rc = (r < B) ? r : (B - 1);
        idxr[k] = (lane < FN) ? (x[rc * FN + lane] + lane * FIELD_SIZE) : 0;
    }

    // ---- per-lane weight constants (amortized over RPW rows) ----
    bf16x8 aW;                          // A-frag: W^T[a=col][k=e0+i]
#pragma unroll
    for (int i = 0; i < 8; ++i) aW[i] = f2bf(attn_W[(e0 + i) * AS + col]);
    // bias directly as the MFMA C operand (no per-tile copy):
    // D rows: a = (r&3) + 8*(r>>2) + 4*half
    f32x16 biasC;
    f32x2  pw2[8];
#pragma unroll
    for (int r = 0; r < 16; ++r) {
        const int a = (r & 3) + 8 * (r >> 2) + 4 * half;
        biasC[r] = attn_b[a];
    }
#pragma unroll
    for (int r2 = 0; r2 < 8; ++r2) {
        const int a0 = (2 * r2 & 3) + 8 * (2 * r2 >> 2) + 4 * half; // pairs a0,a0+1
        pw2[r2].x = proj_w[a0];
        pw2[r2].y = proj_w[a0 + 1];
    }
    f32x2 fcw2[4];
#pragma unroll
    for (int i = 0; i < 4; ++i) {
        fcw2[i].x = fc_w[e0 + 2 * i];
        fcw2[i].y = fc_w[e0 + 2 * i + 1];
    }
    const float cbias = linear_bias[0] + fc_b[0];

    // ---- prologue: row 0 gather + LDS write ----
    float linv = (lane < FN) ? linear_table[idxr[0]] : 0.f;
    {
        float4 ga, gb;
        gather_embed(embed_table, idxr[0], lane, ga, gb);
        write_embed(emb_s[wave][0], lane, ga, gb);
    }

    __syncthreads();                    // pko_s ready
    int pk[NT];
#pragma unroll
    for (int t = 0; t < NT; ++t) pk[t] = pko_s[t * 32 + col];

    // ---- main loop over this wave's rows ----
#pragma unroll
    for (int k = 0; k < RPW; ++k) {
        const int row = w0 + k;
        // prefetch next row (gather overlaps this row's compute)
        float4 na, nb; float linn = 0.f;
        if (k + 1 < RPW) {
            linn = (lane < FN) ? linear_table[idxr[k + 1]] : 0.f;
            gather_embed(embed_table, idxr[k + 1], lane, na, nb);
        }

        const char* embb = (const char*)emb_s[wave][k & 1] + half * 32;
        float m = -FLT_MAX, ssum = 0.f, gacc = 0.f;
#pragma unroll
        for (int t = 0; t < NT; ++t) {
            const int oi = pk[t] >> 16;
            const int oj = pk[t] & 0xffff;
            F4P xi0, xi1, xj0, xj1;
            xi0.f4 = *(const float4*)(embb + oi);
            xi1.f4 = *(const float4*)(embb + oi + 16);
            xj0.f4 = *(const float4*)(embb + oj);
            xj1.f4 = *(const float4*)(embb + oj + 16);
            // packed products: 4 v_pk_mul_f32
            const f32x2 P0 = xi0.p[0] * xj0.p[0];
            const f32x2 P1 = xi0.p[1] * xj0.p[1];
            const f32x2 P2 = xi1.p[0] * xj1.p[0];
            const f32x2 P3 = xi1.p[1] * xj1.p[1];
            // fc-dot: 4 v_pk_fma_f32 + 1 hadd
            f32x2 G = P0 * fcw2[0];
            G = __builtin_elementwise_fma(P1, fcw2[1], G);
            G = __builtin_elementwise_fma(P2, fcw2[2], G);
            G = __builtin_elementwise_fma(P3, fcw2[3], G);
            const float gv = G.x + G.y;
            // bf16 truncation pack: 4 v_perm
            BFR u;
            u.i[0] = __builtin_amdgcn_perm(__float_as_int(P0.y), __float_as_int(P0.x), 0x07060302);
            u.i[1] = __builtin_amdgcn_perm(__float_as_int(P1.y), __float_as_int(P1.x), 0x07060302);
            u.i[2] = __builtin_amdgcn_perm(__float_as_int(P2.y), __float_as_int(P2.x), 0x07060302);
            u.i[3] = __builtin_amdgcn_perm(__float_as_int(P3.y), __float_as_int(P3.x), 0x07060302);
            // bias rides in as C; D gets fresh regs (no init movs)
            const f32x16 c = __builtin_amdgcn_mfma_f32_32x32x16_bf16(aW, u.v, biasC, 0, 0, 0);
            f32x2 sac; sac.x = 0.f; sac.y = 0.f;
            f32x2 z2;  z2.x = 0.f;  z2.y = 0.f;
#pragma unroll
            for (int r2 = 0; r2 < 8; ++r2) {
                f32x2 h; h.x = c[2 * r2]; h.y = c[2 * r2 + 1];
                h = __builtin_elementwise_max(h, z2);
                sac = __builtin_elementwise_fma(h, pw2[r2], sac);
            }
            float s = sac.x + sac.y;
            s += __shfl_xor(s, 32, 64);        // combine the two a-halves
            const bool valid = (t < NT - 1) || (col < LASTV);
            s = valid ? s : -FLT_MAX;
            // online softmax update (3 live scalars)
            const float mn   = fmaxf(m, s);
            const float cold = __expf(m - mn);
            const float e    = __expf(s - mn);
            ssum = fmaf(ssum, cold, e);
            gacc = fmaf(gacc, cold, e * gv);
            m = mn;
        }

        // ---- reductions: max (half), rescale, sums ----
        float M = m;
#pragma unroll
        for (int off = 16; off; off >>= 1) M = fmaxf(M, __shfl_xor(M, off, 64));
        const float rs = __expf(m - M);
        ssum *= rs; gacc *= rs;
#pragma unroll
        for (int off = 16; off; off >>= 1) ssum += __shfl_xor(ssum, off, 64);
#pragma unroll
        for (int off = 32; off; off >>= 1) gacc += __shfl_xor(gacc, off, 64);
        float lin = linv;
#pragma unroll
        for (int off = 32; off; off >>= 1) lin += __shfl_xor(lin, off, 64);

        if (row < B && lane == 0)
            out[row] = lin + cbias + gacc / ssum;

        // stage next row's embeddings into the other buffer
        if (k + 1 < RPW) {
            write_embed(emb_s[wave][(k + 1) & 1], lane, na, nb);
            linv = linn;
        }
    }
}

extern "C" void kernel_launch(void* const* d_in, const int* in_sizes, int n_in,
                              void* d_out, int out_size, void* d_ws, size_t ws_size,
                              hipStream_t stream) {
    const int*   x            = (const int*)  d_in[0];
    const float* embed_table  = (const float*)d_in[1];
    const float* linear_table = (const float*)d_in[2];
    const float* linear_bias  = (const float*)d_in[3];
    const float* attn_W       = (const float*)d_in[4];
    const float* attn_b       = (const float*)d_in[5];
    const float* proj_w       = (const float*)d_in[6];
    // d_in[7] = proj_b (softmax-invariant)
    const float* fc_w         = (const float*)d_in[8];
    const float* fc_b         = (const float*)d_in[9];
    float* out = (float*)d_out;

    const int B = in_sizes[0] / FN;
    const int rows_per_block = (NTHR / 64) * RPW;   // 8
    const int grid = (B + rows_per_block - 1) / rows_per_block;
    afm_kernel<<<grid, NTHR, 0, stream>>>(x, embed_table, linear_table,
                                          linear_bias, attn_W, attn_b, proj_w,
                                          fc_w, fc_b, out, B);
}